// Round 3
// baseline (642.381 us; speedup 1.0000x reference)
//
#include <hip/hip_runtime.h>
#include <hip/hip_bf16.h>

typedef unsigned short u16;
typedef __attribute__((ext_vector_type(8))) short bf16x8;
typedef __attribute__((ext_vector_type(4))) float f32x4;
typedef __attribute__((ext_vector_type(4))) unsigned short u16x4;
typedef __attribute__((ext_vector_type(4))) unsigned int u32x4;

__device__ __forceinline__ u16 f2bf(float f) {
    unsigned u = __float_as_uint(f);
    u += 0x7fffu + ((u >> 16) & 1u);
    return (u16)(u >> 16);
}
__device__ __forceinline__ float bf2f(u16 u) {
    return __uint_as_float(((unsigned)u) << 16);
}

// ---------------- weight transpose + convert: Wt[n][k] = bf16(W[k][n]) ----------
__global__ __launch_bounds__(256)
void wt_kernel(const float* __restrict__ Wq, const float* __restrict__ Wk,
               const float* __restrict__ Wv, const float* __restrict__ Wo,
               u16* __restrict__ Wt) {
    const float* W = blockIdx.z == 0 ? Wq : blockIdx.z == 1 ? Wk : blockIdx.z == 2 ? Wv : Wo;
    u16* Out = Wt + (size_t)blockIdx.z * (1024 * 1024);
    __shared__ float T[64][65];
    const int t = threadIdx.x;
    const int r0 = blockIdx.y * 64, c0 = blockIdx.x * 64;
#pragma unroll
    for (int e = 0; e < 4; ++e) {
        int row = e * 16 + (t >> 4), c4 = (t & 15) * 4;
        f32x4 v = *(const f32x4*)(W + (r0 + row) * 1024 + c0 + c4);
        T[row][c4] = v[0]; T[row][c4 + 1] = v[1]; T[row][c4 + 2] = v[2]; T[row][c4 + 3] = v[3];
    }
    __syncthreads();
#pragma unroll
    for (int e = 0; e < 4; ++e) {
        int orow = e * 16 + (t >> 4), oc4 = (t & 15) * 4;
        u16x4 pk = { f2bf(T[oc4][orow]), f2bf(T[oc4 + 1][orow]),
                     f2bf(T[oc4 + 2][orow]), f2bf(T[oc4 + 3][orow]) };
        *(u16x4*)(Out + (c0 + orow) * 1024 + r0 + oc4) = pk;
    }
}

// ---------------- GEMM: C[8192][1024] = A[8192][1024] * W  (Bt = W^T bf16) ------
// AF32: A fp32 (convert in staging), else bf16. BIAS: add bias, write FP32 to Cf;
// else write bf16 to Cb.
template <int AF32, int BIAS>
__global__ __launch_bounds__(256)
void gemm_kernel(const void* __restrict__ Av, const u16* __restrict__ Bt,
                 u16* __restrict__ Cb, float* __restrict__ Cf,
                 const float* __restrict__ bias) {
    constexpr int K = 1024;
    __shared__ u16 As[128 * 64];
    __shared__ u16 Bs[128 * 64];
    const int tid = threadIdx.x;
    const int lane = tid & 63, w = tid >> 6;
    const int wr = w >> 1, wc = w & 1;
    const int c = lane & 15, g = lane >> 4;
    const int m0 = blockIdx.y * 128, n0 = blockIdx.x * 128;
    const float* Af = (const float*)Av;
    const u16* Ab = (const u16*)Av;
    f32x4 acc[4][4] = {};
    for (int kt = 0; kt < 16; ++kt) {
        const int k0 = kt * 64;
        if (AF32) {
#pragma unroll
            for (int i = 0; i < 8; ++i) {
                int idx = i * 256 + tid;
                int row = idx >> 4, c4 = (idx & 15) * 4;
                f32x4 v = *(const f32x4*)(Af + (m0 + row) * K + k0 + c4);
                u16x4 pk = { f2bf(v[0]), f2bf(v[1]), f2bf(v[2]), f2bf(v[3]) };
                *(u16x4*)&As[row * 64 + c4] = pk;
            }
        } else {
#pragma unroll
            for (int i = 0; i < 4; ++i) {
                int idx = i * 256 + tid;
                int row = idx >> 3, c8 = (idx & 7) * 8;
                u32x4 v = *(const u32x4*)(Ab + (m0 + row) * K + k0 + c8);
                *(u32x4*)&As[row * 64 + c8] = v;
            }
        }
#pragma unroll
        for (int i = 0; i < 4; ++i) {
            int idx = i * 256 + tid;
            int row = idx >> 3, c8 = (idx & 7) * 8;
            u32x4 v = *(const u32x4*)(Bt + (n0 + row) * K + k0 + c8);
            *(u32x4*)&Bs[row * 64 + c8] = v;
        }
        __syncthreads();
#pragma unroll
        for (int kk = 0; kk < 2; ++kk) {
            bf16x8 af[4], bfr[4];
#pragma unroll
            for (int m = 0; m < 4; ++m)
                af[m] = *(const bf16x8*)&As[(wr * 64 + m * 16 + c) * 64 + kk * 32 + 8 * g];
#pragma unroll
            for (int n = 0; n < 4; ++n)
                bfr[n] = *(const bf16x8*)&Bs[(wc * 64 + n * 16 + c) * 64 + kk * 32 + 8 * g];
#pragma unroll
            for (int m = 0; m < 4; ++m)
#pragma unroll
                for (int n = 0; n < 4; ++n)
                    acc[m][n] = __builtin_amdgcn_mfma_f32_16x16x32_bf16(af[m], bfr[n], acc[m][n], 0, 0, 0);
        }
        __syncthreads();
    }
#pragma unroll
    for (int n = 0; n < 4; ++n) {
        int col = n0 + wc * 64 + n * 16 + c;
        float bv = BIAS ? bias[col] : 0.0f;
#pragma unroll
        for (int m = 0; m < 4; ++m) {
            int row0 = m0 + wr * 64 + m * 16 + 4 * g;
#pragma unroll
            for (int r = 0; r < 4; ++r) {
                if (BIAS) Cf[(row0 + r) * 1024 + col] = acc[m][n][r] + bv;
                else      Cb[(row0 + r) * 1024 + col] = f2bf(acc[m][n][r]);
            }
        }
    }
}

// ---------------- LayerNorm over D=1024 (bf16 in), write bf16 [bh][s][hd] -------
__global__ __launch_bounds__(256)
void ln_kernel(const u16* __restrict__ P, const float* __restrict__ gamma,
               const float* __restrict__ beta, float mul, u16* __restrict__ Out) {
    const int row = blockIdx.x;
    const int tid = threadIdx.x;
    const int lane = tid & 63, w = tid >> 6;
    u16x4 xr = *(const u16x4*)(P + row * 1024 + tid * 4);
    float x0 = bf2f(xr[0]), x1 = bf2f(xr[1]), x2 = bf2f(xr[2]), x3 = bf2f(xr[3]);
    float s = x0 + x1 + x2 + x3;
    float sq = x0 * x0 + x1 * x1 + x2 * x2 + x3 * x3;
#pragma unroll
    for (int m = 1; m < 64; m <<= 1) { s += __shfl_xor(s, m); sq += __shfl_xor(sq, m); }
    __shared__ float red[8];
    if (lane == 0) { red[w] = s; red[4 + w] = sq; }
    __syncthreads();
    float st = red[0] + red[1] + red[2] + red[3];
    float sqt = red[4] + red[5] + red[6] + red[7];
    float mu = st * (1.0f / 1024.0f);
    float var = sqt * (1.0f / 1024.0f) - mu * mu;
    float rs = rsqrtf(var + 1e-5f);
    f32x4 gm = *(const f32x4*)(gamma + tid * 4);
    f32x4 bt = *(const f32x4*)(beta + tid * 4);
    float xs[4] = {x0, x1, x2, x3};
    u16x4 pk;
#pragma unroll
    for (int j = 0; j < 4; ++j)
        pk[j] = f2bf(((xs[j] - mu) * rs * gm[j] + bt[j]) * mul);
    const int b = row >> 11, sI = row & 2047;
    const int col = tid * 4, hh = col >> 6, d = col & 63;
    *(u16x4*)(Out + (((b * 16 + hh) * 2048 + sI) << 6) + d) = pk;
}

// ---------------- V transpose: Vt[bh][64][S] (bf16 in/out) ----------------------
__global__ __launch_bounds__(256)
void vt_kernel(const u16* __restrict__ P, u16* __restrict__ Vt) {
    __shared__ u16 T[64][72];
    const int t = threadIdx.x;
    const int bh = blockIdx.y, s0 = blockIdx.x * 64;
    const int b = bh >> 4, h = bh & 15;
#pragma unroll
    for (int e = 0; e < 4; ++e) {
        int row = e * 16 + (t >> 4), c4 = (t & 15) * 4;
        u16x4 v = *(const u16x4*)(P + (b * 2048 + s0 + row) * 1024 + h * 64 + c4);
        *(u16x4*)&T[row][c4] = v;
    }
    __syncthreads();
#pragma unroll
    for (int e = 0; e < 4; ++e) {
        int dd = e * 16 + (t >> 4), s4 = (t & 15) * 4;
        u16x4 pk = { T[s4][dd], T[s4 + 1][dd], T[s4 + 2][dd], T[s4 + 3][dd] };
        *(u16x4*)(Vt + ((size_t)bh * 64 + dd) * 2048 + s0 + s4) = pk;
    }
}

// ---------------- flash attention: 4 independent waves, 16 q-rows each ----------
__global__ __launch_bounds__(256)
void attn_kernel(const u16* __restrict__ Qa, const u16* __restrict__ Ka,
                 const u16* __restrict__ Vt, u16* __restrict__ Xa) {
    __shared__ u16 Pl[4 * 16 * 136];
    const int tid = threadIdx.x;
    const int lane = tid & 63, w = tid >> 6;
    const int c = lane & 15, g = lane >> 4;
    const int bh = blockIdx.y, q0 = blockIdx.x * 64;
    const int b = bh >> 4, h = bh & 15;
    const int qrow = q0 + w * 16 + c;
    const u16* qptr = Qa + (bh * 2048 + qrow) * 64;
    bf16x8 qf0 = *(const bf16x8*)(qptr + 8 * g);
    bf16x8 qf1 = *(const bf16x8*)(qptr + 32 + 8 * g);
    f32x4 o[4] = {};
    float mx[4] = {-1e30f, -1e30f, -1e30f, -1e30f};
    float li[4] = {0.f, 0.f, 0.f, 0.f};
    u16* pbase = &Pl[w * 16 * 136];
    for (int t = 0; t < 16; ++t) {
        const int kb = t * 128;
        f32x4 sacc[8] = {};
        const u16* kp = Ka + (bh * 2048 + kb + c) * 64 + 8 * g;
#pragma unroll
        for (int ct = 0; ct < 8; ++ct) {
            bf16x8 kf0 = *(const bf16x8*)(kp + ct * 16 * 64);
            bf16x8 kf1 = *(const bf16x8*)(kp + ct * 16 * 64 + 32);
            sacc[ct] = __builtin_amdgcn_mfma_f32_16x16x32_bf16(qf0, kf0, sacc[ct], 0, 0, 0);
            sacc[ct] = __builtin_amdgcn_mfma_f32_16x16x32_bf16(qf1, kf1, sacc[ct], 0, 0, 0);
        }
#pragma unroll
        for (int r = 0; r < 4; ++r) {
            float tm = sacc[0][r];
#pragma unroll
            for (int ct = 1; ct < 8; ++ct) tm = fmaxf(tm, sacc[ct][r]);
            tm = fmaxf(tm, __shfl_xor(tm, 1));
            tm = fmaxf(tm, __shfl_xor(tm, 2));
            tm = fmaxf(tm, __shfl_xor(tm, 4));
            tm = fmaxf(tm, __shfl_xor(tm, 8));
            float nm = fmaxf(mx[r], tm);
            float fr = exp2f(mx[r] - nm);
            mx[r] = nm;
            const int qh = 4 * g + r;
            float ts = 0.f;
#pragma unroll
            for (int ct = 0; ct < 8; ++ct) {
                float p = exp2f(sacc[ct][r] - nm);
                ts += p;
                pbase[qh * 136 + ct * 16 + c] = f2bf(p);
            }
            ts += __shfl_xor(ts, 1);
            ts += __shfl_xor(ts, 2);
            ts += __shfl_xor(ts, 4);
            ts += __shfl_xor(ts, 8);
            li[r] = li[r] * fr + ts;
            o[0][r] *= fr; o[1][r] *= fr; o[2][r] *= fr; o[3][r] *= fr;
        }
        __syncthreads();
#pragma unroll
        for (int s4 = 0; s4 < 4; ++s4) {
            bf16x8 af = *(const bf16x8*)&pbase[c * 136 + 32 * s4 + 8 * g];
            const u16* vp = Vt + ((size_t)bh * 64 + c) * 2048 + kb + 32 * s4 + 8 * g;
#pragma unroll
            for (int n = 0; n < 4; ++n) {
                bf16x8 vf = *(const bf16x8*)(vp + n * 16 * 2048);
                o[n] = __builtin_amdgcn_mfma_f32_16x16x32_bf16(af, vf, o[n], 0, 0, 0);
            }
        }
        __syncthreads();
    }
#pragma unroll
    for (int r = 0; r < 4; ++r) {
        float inv = 1.0f / li[r];
        int row = q0 + w * 16 + 4 * g + r;
        u16* xp = Xa + (b * 2048 + row) * 1024 + h * 64;
#pragma unroll
        for (int n = 0; n < 4; ++n)
            xp[n * 16 + c] = f2bf(o[n][r] * inv);
    }
}

// ---------------- launch --------------------------------------------------------
extern "C" void kernel_launch(void* const* d_in, const int* in_sizes, int n_in,
                              void* d_out, int out_size, void* d_ws, size_t ws_size,
                              hipStream_t stream) {
    const float* q   = (const float*)d_in[0];
    const float* k   = (const float*)d_in[1];
    const float* v   = (const float*)d_in[2];
    const float* Wq  = (const float*)d_in[3];
    const float* Wk  = (const float*)d_in[4];
    const float* Wv  = (const float*)d_in[5];
    const float* Wo  = (const float*)d_in[6];
    const float* bo  = (const float*)d_in[7];
    const float* qg  = (const float*)d_in[8];
    const float* qbt = (const float*)d_in[9];
    const float* kg  = (const float*)d_in[10];
    const float* kbt = (const float*)d_in[11];

    char* ws = (char*)d_ws;
    u16* Wt = (u16*)(ws);                    //  8,388,608 B
    u16* Pb = (u16*)(ws + 8388608);          // 16,777,216 B
    u16* Qa = (u16*)(ws + 25165824);         // 16,777,216 B
    u16* Ka = (u16*)(ws + 41943040);         // 16,777,216 B
    u16* Vt = (u16*)(ws + 58720256);         // 16,777,216 B (end 75,497,472 = 72 MiB)
    u16* Xa = Pb;                            // reuse: P dead after vt_kernel

    const float MUL_Q = 0.04508422002778f;   // (1/32) * log2(e)

    wt_kernel<<<dim3(16, 16, 4), 256, 0, stream>>>(Wq, Wk, Wv, Wo, Wt);

    gemm_kernel<1, 0><<<dim3(8, 64), 256, 0, stream>>>((const void*)q, Wt, Pb, nullptr, nullptr);
    ln_kernel<<<8192, 256, 0, stream>>>(Pb, qg, qbt, MUL_Q, Qa);

    gemm_kernel<1, 0><<<dim3(8, 64), 256, 0, stream>>>((const void*)k, Wt + 1048576, Pb, nullptr, nullptr);
    ln_kernel<<<8192, 256, 0, stream>>>(Pb, kg, kbt, 1.0f, Ka);

    gemm_kernel<1, 0><<<dim3(8, 64), 256, 0, stream>>>((const void*)v, Wt + 2097152, Pb, nullptr, nullptr);
    vt_kernel<<<dim3(32, 64), 256, 0, stream>>>(Pb, Vt);

    attn_kernel<<<dim3(32, 64), 256, 0, stream>>>(Qa, Ka, Vt, Xa);

    gemm_kernel<0, 1><<<dim3(8, 64), 256, 0, stream>>>((const void*)Xa, Wt + 3145728, nullptr, (float*)d_out, bo);
}